// Round 1
// baseline (37.997 us; speedup 1.0000x reference)
//
#include <hip/hip_runtime.h>
#include <math.h>

// FNOGeoEncoder — exact algebraic reduction.
// Only the DC mode (m=0) of the spectral chain reaches the output:
//   S       = sum_t V[t,:]                          (3,)
//   X0[c]   = fc0_w[c,:]. S + N*fc0_b[c]            (256,)
//   X_{k+1} = Re(sc_w[k,:,:,0])^T X_k               (4 matvecs 256x256)
//   feat    = X4 / N
//   z       = tanh(feat@fc1_w^T + fc1_b)@fc2_w^T + fc2_b

constexpr int kN = 131072;
constexpr int kWidth = 256;
constexpr int kModes = 512;
constexpr int kLayers = 4;

__global__ __launch_bounds__(256) void vsum_stage1(const float* __restrict__ V,
                                                   float* __restrict__ partials) {
    __shared__ float sred[3][256];
    int tid = threadIdx.x;
    int gt = blockIdx.x * 256 + tid;  // 0..65535, each handles rows gt and gt+65536
    const float* p0 = V + (size_t)gt * 3;
    const float* p1 = V + (size_t)(gt + 65536) * 3;
    sred[0][tid] = p0[0] + p1[0];
    sred[1][tid] = p0[1] + p1[1];
    sred[2][tid] = p0[2] + p1[2];
    __syncthreads();
    for (int off = 128; off > 0; off >>= 1) {
        if (tid < off) {
            sred[0][tid] += sred[0][tid + off];
            sred[1][tid] += sred[1][tid + off];
            sred[2][tid] += sred[2][tid + off];
        }
        __syncthreads();
    }
    if (tid == 0) {
        partials[blockIdx.x * 3 + 0] = sred[0][0];
        partials[blockIdx.x * 3 + 1] = sred[1][0];
        partials[blockIdx.x * 3 + 2] = sred[2][0];
    }
}

__global__ __launch_bounds__(256) void lift_dc(const float* __restrict__ partials,
                                               const float* __restrict__ fc0_w,
                                               const float* __restrict__ fc0_b,
                                               float* __restrict__ X0) {
    __shared__ float red[256];
    __shared__ float S[3];
    int tid = threadIdx.x;
    for (int j = 0; j < 3; ++j) {
        red[tid] = partials[tid * 3 + j];
        __syncthreads();
        for (int off = 128; off > 0; off >>= 1) {
            if (tid < off) red[tid] += red[tid + off];
            __syncthreads();
        }
        if (tid == 0) S[j] = red[0];
        __syncthreads();
    }
    float x = S[0] * fc0_w[tid * 3 + 0] + S[1] * fc0_w[tid * 3 + 1] +
              S[2] * fc0_w[tid * 3 + 2] + (float)kN * fc0_b[tid];
    X0[tid] = x;
}

// One spectral layer at DC: Xout[o] = sum_c Re(w[c,o,0]) * Xin[c]
// w points at sc_w[layer]; element [c][o][0][0] is at ((c*256+o)*512)*2 floats.
__global__ __launch_bounds__(256) void spectral_dc(const float* __restrict__ w,
                                                   const float* __restrict__ Xin,
                                                   float* __restrict__ Xout) {
    int o = blockIdx.x, c = threadIdx.x;
    size_t off = (((size_t)c * kWidth + o) * (size_t)kModes) * 2;
    float v = w[off] * Xin[c];
    __shared__ float red[256];
    red[c] = v;
    __syncthreads();
    for (int s = 128; s > 0; s >>= 1) {
        if (c < s) red[c] += red[c + s];
        __syncthreads();
    }
    if (c == 0) Xout[o] = red[0];
}

__global__ __launch_bounds__(256) void head(const float* __restrict__ X4,
                                            const float* __restrict__ fc1_w,
                                            const float* __restrict__ fc1_b,
                                            const float* __restrict__ fc2_w,
                                            const float* __restrict__ fc2_b,
                                            float* __restrict__ out) {
    __shared__ float feat[256];
    __shared__ float h[128];
    int t = threadIdx.x;
    feat[t] = X4[t] * (1.0f / (float)kN);
    __syncthreads();
    if (t < 128) {
        float acc = fc1_b[t];
        #pragma unroll 8
        for (int o = 0; o < 256; ++o) acc += feat[o] * fc1_w[t * 256 + o];
        h[t] = tanhf(acc);
    }
    __syncthreads();
    float acc = fc2_b[t];
    #pragma unroll 8
    for (int j = 0; j < 128; ++j) acc += h[j] * fc2_w[t * 128 + j];
    out[t] = acc;
}

extern "C" void kernel_launch(void* const* d_in, const int* in_sizes, int n_in,
                              void* d_out, int out_size, void* d_ws, size_t ws_size,
                              hipStream_t stream) {
    const float* V     = (const float*)d_in[0];
    const float* fc0_w = (const float*)d_in[1];
    const float* fc0_b = (const float*)d_in[2];
    const float* sc_w  = (const float*)d_in[3];
    const float* fc1_w = (const float*)d_in[4];
    const float* fc1_b = (const float*)d_in[5];
    const float* fc2_w = (const float*)d_in[6];
    const float* fc2_b = (const float*)d_in[7];
    float* out = (float*)d_out;

    float* ws = (float*)d_ws;
    float* partials = ws;        // 256*3 floats
    float* Xa = ws + 1024;       // 256 floats
    float* Xb = ws + 1280;       // 256 floats

    vsum_stage1<<<256, 256, 0, stream>>>(V, partials);
    lift_dc<<<1, 256, 0, stream>>>(partials, fc0_w, fc0_b, Xa);

    const size_t layer_stride = (size_t)kWidth * kWidth * kModes * 2;
    float* bufs[2] = {Xa, Xb};
    for (int i = 0; i < kLayers; ++i) {
        spectral_dc<<<256, 256, 0, stream>>>(sc_w + (size_t)i * layer_stride,
                                             bufs[i & 1], bufs[(i + 1) & 1]);
    }
    head<<<1, 256, 0, stream>>>(bufs[kLayers & 1], fc1_w, fc1_b, fc2_w, fc2_b, out);
}

// Round 2
// 36.774 us; speedup vs baseline: 1.0333x; 1.0333x over previous
//
#include <hip/hip_runtime.h>
#include <math.h>

// FNOGeoEncoder — exact algebraic reduction (only DC mode survives the mean):
//   S       = sum_t V[t,:]                          (3,)
//   X0[c]   = fc0_w[c,:].S + N*fc0_b[c]             (256,)
//   X_{k+1} = Re(sc_w[k,:,:,0])^T X_k               (4 matvecs 256x256)
//   feat    = X4 / N
//   z       = tanh(feat@fc1_w^T + fc1_b)@fc2_w^T + fc2_b
//
// Structure: the scattered mode-0 weight gather is chain-independent, so
// stage A (full GPU) compacts it + computes V partial sums; stage B (one
// block) runs the whole serial chain through LDS-synced stages.

constexpr int kN = 131072;
constexpr int kWidth = 256;
constexpr int kModes = 512;
constexpr int kLayers = 4;
constexpr size_t kLayerStride = (size_t)kWidth * kWidth * kModes * 2;  // floats
constexpr int kGatherBlocks = 256;   // 256 blk * 256 thr * 4 layers = 262144 gathers
constexpr int kVsumBlocks = 384;     // 384 blk * 256 thr * 1 float4 = 98304 = 131072*3/4

// ws layout (floats):
//   [0, 262144)            compact W[l][c][o]
//   [262144, 262144+1152)  vsum partials [384][3]

__global__ __launch_bounds__(256) void stageA(const float* __restrict__ sc_w,
                                              const float* __restrict__ V,
                                              float* __restrict__ ws) {
    int b = blockIdx.x, t = threadIdx.x;
    if (b < kGatherBlocks) {
        int rem = b * 256 + t;  // flat (c,o), 0..65535; consecutive t -> consecutive o
        const float* src = sc_w + (size_t)rem * (size_t)(kModes * 2);
        #pragma unroll
        for (int l = 0; l < kLayers; ++l) {
            ws[(size_t)l * 65536 + rem] = src[(size_t)l * kLayerStride];
        }
    } else {
        int vb = b - kGatherBlocks;
        int q = vb * 256 + t;  // float4 index, 0..98303
        const float4 v = reinterpret_cast<const float4*>(V)[q];
        int r = q % 3;         // component of first element (f=4q, f%3 == q%3)
        float acc0 = 0.f, acc1 = 0.f, acc2 = 0.f;
        // comps of (x,y,z,w) are r, (r+1)%3, (r+2)%3, r
        float a[3] = {0.f, 0.f, 0.f};
        a[r] = v.x + v.w;
        a[(r + 1) % 3] = v.y;
        a[(r + 2) % 3] = v.z;
        acc0 = a[0]; acc1 = a[1]; acc2 = a[2];
        __shared__ float sred[3][256];
        sred[0][t] = acc0; sred[1][t] = acc1; sred[2][t] = acc2;
        __syncthreads();
        for (int off = 128; off > 0; off >>= 1) {
            if (t < off) {
                sred[0][t] += sred[0][t + off];
                sred[1][t] += sred[1][t + off];
                sred[2][t] += sred[2][t + off];
            }
            __syncthreads();
        }
        if (t == 0) {
            float* partials = ws + 262144;
            partials[vb * 3 + 0] = sred[0][0];
            partials[vb * 3 + 1] = sred[1][0];
            partials[vb * 3 + 2] = sred[2][0];
        }
    }
}

__global__ __launch_bounds__(1024) void stageB(const float* __restrict__ ws,
                                               const float* __restrict__ fc0_w,
                                               const float* __restrict__ fc0_b,
                                               const float* __restrict__ fc1_w,
                                               const float* __restrict__ fc1_b,
                                               const float* __restrict__ fc2_w,
                                               const float* __restrict__ fc2_b,
                                               float* __restrict__ out) {
    __shared__ float red[1024];
    __shared__ float xbuf[256];
    __shared__ float part[4][256];
    __shared__ float S[3];
    __shared__ float hbuf[128];
    int t = threadIdx.x;
    const float* partials = ws + 262144;

    // S[j] = fixed-order tree sum of partials[384][j]
    for (int j = 0; j < 3; ++j) {
        red[t] = (t < kVsumBlocks) ? partials[t * 3 + j] : 0.f;
        __syncthreads();
        for (int off = 512; off > 0; off >>= 1) {
            if (t < off) red[t] += red[t + off];
            __syncthreads();
        }
        if (t == 0) S[j] = red[0];
        __syncthreads();
    }

    // lift at DC
    if (t < 256) {
        xbuf[t] = S[0] * fc0_w[t * 3] + S[1] * fc0_w[t * 3 + 1] +
                  S[2] * fc0_w[t * 3 + 2] + (float)kN * fc0_b[t];
    }
    __syncthreads();

    // 4 spectral-DC matvecs, split-K by 4 wave-groups
    int g = t >> 8, o = t & 255;
    for (int l = 0; l < kLayers; ++l) {
        const float* W = ws + (size_t)l * 65536;
        float acc = 0.f;
        int c0 = g * 64;
        #pragma unroll 8
        for (int i = 0; i < 64; ++i) {
            int c = c0 + i;
            acc += W[c * 256 + o] * xbuf[c];  // coalesced across o per iteration
        }
        part[g][o] = acc;
        __syncthreads();
        if (t < 256) xbuf[t] = part[0][t] + part[1][t] + part[2][t] + part[3][t];
        __syncthreads();
    }

    // feat = X4 / N
    if (t < 256) xbuf[t] *= (1.0f / (float)kN);
    __syncthreads();

    // fc1 + tanh: 128 outputs, split-K by 8
    {
        int j = t & 127, s = t >> 7;
        float acc = 0.f;
        int c0 = s * 32;
        #pragma unroll 8
        for (int i = 0; i < 32; ++i) acc += xbuf[c0 + i] * fc1_w[j * 256 + c0 + i];
        red[s * 128 + j] = acc;
        __syncthreads();
        if (t < 128) {
            float a = 0.f;
            #pragma unroll
            for (int s2 = 0; s2 < 8; ++s2) a += red[s2 * 128 + t];
            hbuf[t] = tanhf(a + fc1_b[t]);
        }
        __syncthreads();
    }

    // fc2: 256 outputs, split-K by 4
    {
        int k = t & 255, s = t >> 8;
        float acc = 0.f;
        int c0 = s * 32;
        #pragma unroll 8
        for (int i = 0; i < 32; ++i) acc += hbuf[c0 + i] * fc2_w[k * 128 + c0 + i];
        red[s * 256 + k] = acc;
        __syncthreads();
        if (t < 256) out[t] = red[t] + red[256 + t] + red[512 + t] + red[768 + t] + fc2_b[t];
    }
}

extern "C" void kernel_launch(void* const* d_in, const int* in_sizes, int n_in,
                              void* d_out, int out_size, void* d_ws, size_t ws_size,
                              hipStream_t stream) {
    const float* V     = (const float*)d_in[0];
    const float* fc0_w = (const float*)d_in[1];
    const float* fc0_b = (const float*)d_in[2];
    const float* sc_w  = (const float*)d_in[3];
    const float* fc1_w = (const float*)d_in[4];
    const float* fc1_b = (const float*)d_in[5];
    const float* fc2_w = (const float*)d_in[6];
    const float* fc2_b = (const float*)d_in[7];
    float* out = (float*)d_out;
    float* ws = (float*)d_ws;

    stageA<<<kGatherBlocks + kVsumBlocks, 256, 0, stream>>>(sc_w, V, ws);
    stageB<<<1, 1024, 0, stream>>>(ws, fc0_w, fc0_b, fc1_w, fc1_b, fc2_w, fc2_b, out);
}